// Round 6
// baseline (741.031 us; speedup 1.0000x reference)
//
#include <hip/hip_runtime.h>
#include <cstdint>
#include <cstddef>

// dec: [16, 3999, 512] fp32, wgt: [16, 512] fp32, out: [16, 32000] fp32
//   est[f][w] = dot(dec[f], wgt[w]);  out[8g+i] = est[g][i] + est[g-1][8+i]
//
// R12: COALESCED direct loads. Lane remap: kappa = lane&15 (k-phase),
// fg = lane>>4 (frame). Each wave-instruction reads 4 frames x 256 B
// contiguous = 16 fully-consumed cache lines (same footprint as the
// 6.3 TB/s copy ubench), vs the old lane=frame pattern's 64 distinct
// lines/instr, which caps at ~2.2 TB/s (per-CU in-flight-line budget x
// HBM latency -- fits all R6-R11 measurements).
//   Cost of coalescing: weight index now depends on kappa -> weights come
//   from LDS (staged once, 32 KB), amortized over 16 slots/wave so the
//   LDS-read budget stays ~10 us/CU (16 b128 per u serve 256 FMAs).
//   k-split partials reduce across the 16 kappa-lanes via a 4-step
//   __shfl_xor butterfly; compile-time w loop + predicated kappa==w write
//   avoids runtime-indexed register arrays (-> scratch).
// No barriers in the main loop; one after weight staging, one before OA.

#define NBC     16
#define FRAMES  3999
#define EE      512
#define TOUT    32000
#define NGROUP  4000
#define GPB     63      // output groups per block (64 frame-slots)
#define RSTR    65      // red row stride (pad)

__global__ __launch_bounds__(256, 3) void decoder_kernel(
    const float* __restrict__ dec,
    const float* __restrict__ wgt,
    float* __restrict__ out)
{
    __shared__ __align__(16) float wl[16 * EE];   // 32 KB weights
    __shared__ float red[16 * RSTR];              // est[w][slot], padded

    const int tid   = threadIdx.x;
    const int bc    = blockIdx.y;        // 0..15
    const int chunk = blockIdx.x;        // 0..63
    const int g0    = chunk * GPB;

    const int lane  = tid & 63;
    const int h     = tid >> 6;          // wave 0..3
    const int kappa = lane & 15;         // k-phase within frame
    const int fg    = lane >> 4;         // frame sub-group 0..3

    // ---- stage weights into LDS (coalesced, once) ----
    {
        const float4* ws = (const float4*)wgt;
        float4*       wd = (float4*)wl;
        #pragma unroll
        for (int i = 0; i < 8; ++i)
            wd[tid + 256 * i] = ws[tid + 256 * i];
    }
    __syncthreads();

    // ---- this wave's 16 slots: slot = h*16 + p*4 + fg ----
    const float* decb = dec + (size_t)bc * FRAMES * EE;
    int   slot[4];
    float msk[4];
    const float* xp[4];
    #pragma unroll
    for (int p = 0; p < 4; ++p) {
        slot[p] = h * 16 + p * 4 + fg;
        const int f = g0 - 1 + slot[p];
        msk[p] = (f >= 0 && f < FRAMES) ? 1.0f : 0.0f;
        const int fr = min(max(f, 0), FRAMES - 1);
        // lane kappa's 16 B stripe; 16-lane group covers 256 B contiguous
        xp[p] = decb + (size_t)fr * EE + kappa * 4;
    }

    float acc[4][16];
    #pragma unroll
    for (int p = 0; p < 4; ++p)
        #pragma unroll
        for (int w = 0; w < 16; ++w) acc[p][w] = 0.f;

    // ---- main loop: u = k-block of 64 floats; no barriers ----
    #pragma unroll
    for (int u = 0; u < 8; ++u) {
        float4 xv[4];
        #pragma unroll
        for (int p = 0; p < 4; ++p)
            xv[p] = *(const float4*)(xp[p] + u * 64);

        #pragma unroll
        for (int wh = 0; wh < 2; ++wh) {
            float4 wv[8];
            #pragma unroll
            for (int w8 = 0; w8 < 8; ++w8)
                wv[w8] = *(const float4*)(wl + (wh * 8 + w8) * EE
                                             + u * 64 + kappa * 4);
            #pragma unroll
            for (int p = 0; p < 4; ++p)
                #pragma unroll
                for (int w8 = 0; w8 < 8; ++w8)
                    acc[p][wh * 8 + w8] += xv[p].x * wv[w8].x
                                         + xv[p].y * wv[w8].y
                                         + xv[p].z * wv[w8].z
                                         + xv[p].w * wv[w8].w;
        }
    }

    // ---- reduce over the 16 kappa-lanes; lane kappa==w writes est ----
    #pragma unroll
    for (int p = 0; p < 4; ++p) {
        #pragma unroll
        for (int w = 0; w < 16; ++w) {
            float v = acc[p][w];
            v += __shfl_xor(v, 1);
            v += __shfl_xor(v, 2);
            v += __shfl_xor(v, 4);
            v += __shfl_xor(v, 8);
            if (kappa == w)                       // 4 lanes (one per fg)
                red[w * RSTR + slot[p]] = v * msk[p];
        }
    }
    __syncthreads();

    // ---- fused overlap-add: 504 outputs, 256 threads -> 2 iterations ----
    for (int o = tid; o < GPB * 8; o += 256) {
        const int j = o >> 3;            // group offset in block, 0..62
        const int i = o & 7;             // sample within group
        const int g = g0 + j;
        if (g < NGROUP)
            out[(size_t)bc * TOUT + g * 8 + i]
                = red[i * RSTR + (j + 1)]        // est[g][i]
                + red[(8 + i) * RSTR + j];       // est[g-1][8+i]
    }
}

extern "C" void kernel_launch(void* const* d_in, const int* in_sizes, int n_in,
                              void* d_out, int out_size, void* d_ws, size_t ws_size,
                              hipStream_t stream) {
    const float* dec = (const float*)d_in[0];   // [8,2,3999,512] fp32
    const float* wgt = (const float*)d_in[1];   // [16,512] fp32
    float* out = (float*)d_out;                 // [8,2,32000] fp32

    decoder_kernel<<<dim3(64, 16), dim3(256), 0, stream>>>(dec, wgt, out);
}